// Round 3
// baseline (356.378 us; speedup 1.0000x reference)
//
#include <hip/hip_runtime.h>
#include <cmath>
#include <complex>

namespace {

constexpr int TLEN   = 65536;
constexpr int NCH    = 512;            // 32*16 channels
constexpr size_t YB_ROWS = 16400;      // quad-rows per slab (valid data rows <= 16398)

// yb layout (slab-major): slab mt (64 ch), row r, ch l, slot q ->
//   float offset ((mt*YB_ROWS + r)*256) + l*4 + q.
// Sample e lives at row s>>2, slot s&3 with s = e+5. Each wave's store stream
// is sequential 1KB-contiguous (row r -> r+1 advances +1KB). ot2 same scheme
// with 4096 quad-rows per slab.

struct Coefs {
  float b0,b1,b2,b3,b4,b5,b6,b7,b8;
  float na1,na2,na3,na4,na5,na6,na7,na8;   // -a[1..8]
  float zi0,zi1,zi2,zi3,zi4,zi5,zi6,zi7;
};

#define IIR_STEP(xv, yv)                                  \
  do {                                                    \
    yv = fmaf(cf.b0, (xv), z0);                           \
    z0 = fmaf(cf.na1, yv, fmaf(cf.b1, (xv), z1));         \
    z1 = fmaf(cf.na2, yv, fmaf(cf.b2, (xv), z2));         \
    z2 = fmaf(cf.na3, yv, fmaf(cf.b3, (xv), z3));         \
    z3 = fmaf(cf.na4, yv, fmaf(cf.b4, (xv), z4));         \
    z4 = fmaf(cf.na5, yv, fmaf(cf.b5, (xv), z5));         \
    z5 = fmaf(cf.na6, yv, fmaf(cf.b6, (xv), z6));         \
    z6 = fmaf(cf.na7, yv, fmaf(cf.b7, (xv), z7));         \
    z7 = fmaf(cf.na8, yv, cf.b8 * (xv));                  \
  } while (0)

// =============== K1: one wave per block, barrier-free forward scan ===========
// Block = 1 wave = 64 channels x one 512-sample chunk (warm-up 253).
// LDS: 2-buffer ring of [64ch][64t] XOR-swizzled subtiles (32.0 KB total ->
// 5 blocks/CU). Swizzle: float4-column col4 stored at col4 ^ (row & 15) --
// same bank balance as +4 padding, zero LDS overhead. No __syncthreads.
template<int QOFF>
__device__ __forceinline__ void run_chunk1(const float* __restrict__ x,
                                           float* __restrict__ yb,
                                           const Coefs& cf,
                                           float (&lds)[2][4096],
                                           int mt, int e0, int nsub,
                                           int store_lo, int store_hi) {
  const int lane   = threadIdx.x;        // 0..63
  const int m0     = mt * 64;
  const int vtbase = e0 - 27;            // x-index of e0
  float4* yq = reinterpret_cast<float4*>(yb);
  const size_t slabq = (size_t)mt * YB_ROWS * 64;   // slab base in float4s
  const int tq  = lane & 15;             // float4-column within a 64t row
  const int chb = lane >> 4;             // base channel (0..3)
  float4 rr[16];                         // staging regs for next subtile

  auto interior = [&](int k) {
    const int vt0 = vtbase + 64 * k;
    return vt0 >= 0 && vt0 + 63 < TLEN;
  };
  // issue: 16 global dwordx4 loads (256B contiguous per 16-lane group)
  auto issue = [&](int k) {
    if (!interior(k)) return;            // boundary subtiles load in commit
    const int vt0 = vtbase + 64 * k;
    const float* p = x + (size_t)(m0 + chb) * TLEN + vt0 + 4 * tq;
#pragma unroll
    for (int pp = 0; pp < 16; ++pp)
      rr[pp] = *reinterpret_cast<const float4*>(p + (size_t)(4 * pp) * TLEN);
  };
  // commit: swizzled ds_write_b128 into [ch][t] tile
  auto commit = [&](int k) {
    float* b = lds[k & 1];
    if (interior(k)) {
#pragma unroll
      for (int pp = 0; pp < 16; ++pp) {
        const int row = chb + 4 * pp;
        *reinterpret_cast<float4*>(&b[row * 64 + 4 * (tq ^ (row & 15))]) = rr[pp];
      }
    } else {
      // boundary: per-lane fixed time index vt; odd-extension via one gather
      const int vt = vtbase + 64 * k + lane;
      const bool lo = vt < 0, hi = vt >= TLEN;
      const int idx  = lo ? -vt : (hi ? 2 * TLEN - 2 - vt : vt);
      const int eidx = hi ? TLEN - 1 : 0;
      const float esc = (lo || hi) ? 2.0f : 0.0f;
      const float msc = (lo || hi) ? -1.0f : 1.0f;
      const float* xr = x + (size_t)m0 * TLEN;
#pragma unroll 8
      for (int ch = 0; ch < 64; ++ch, xr += TLEN)
        b[ch * 64 + 4 * ((lane >> 2) ^ (ch & 15)) + (lane & 3)] =
            fmaf(msc, xr[idx], esc * xr[eidx]);
    }
  };

  issue(0); commit(0);

  float z0 = 0, z1 = 0, z2 = 0, z3 = 0, z4 = 0, z5 = 0, z6 = 0, z7 = 0;
  float4 oq = make_float4(0.f, 0.f, 0.f, 0.f);

  for (int k = 0; k < nsub; ++k) {
    if (k + 1 < nsub) issue(k + 1);      // loads fly while we scan subtile k
    const float* tile = lds[k & 1] + lane * 64;
    if (k == 0) {                        // zi * x_ext(e0); col 0 swizzled
      float x0 = tile[4 * (lane & 15)];
      z0 = cf.zi0 * x0; z1 = cf.zi1 * x0; z2 = cf.zi2 * x0; z3 = cf.zi3 * x0;
      z4 = cf.zi4 * x0; z5 = cf.zi5 * x0; z6 = cf.zi6 * x0; z7 = cf.zi7 * x0;
    }
#pragma unroll
    for (int j = 0; j < 16; ++j) {
      const float4 xv = *reinterpret_cast<const float4*>(tile + 4 * (j ^ (lane & 15)));
      const float xs[4] = {xv.x, xv.y, xv.z, xv.w};
#pragma unroll
      for (int d = 0; d < 4; ++d) {
        float yv; IIR_STEP(xs[d], yv);
        if (QOFF == 1) {                 // c==0 scalar head e=0,1,2 (row 1 q1..3)
          if (k == 0 && j == 0 && d < 3)
            yb[((size_t)mt * YB_ROWS + 1) * 256 + (size_t)lane * 4 + d + 1] = yv;
        }
        const int qq = (4 * j + d + QOFF) & 3;   // static after unroll
        if (qq == 0) oq.x = yv;
        else if (qq == 1) oq.y = yv;
        else if (qq == 2) oq.z = yv;
        else {
          oq.w = yv;
          const int step = 64 * k + 4 * j + d;
          if (step >= store_lo && step <= store_hi)
            yq[slabq + (size_t)((e0 + step + 5) >> 2) * 64 + lane] = oq;
        }
      }
    }
    if (k + 1 < nsub) commit(k + 1);
  }
}

__global__ __launch_bounds__(64) void k_fwd4(const float* __restrict__ x,
                                             float* __restrict__ yb, Coefs cf) {
  __shared__ float lds[2][4096];         // 32.0 KB -> 5 blocks/CU
  // XCD-pin: hw XCD = blockIdx.x % 8. mt = id&7 -> XCD k owns slab k for ALL
  // chunks; consecutive c (overlapping warm-up reads) share that XCD's L2.
  const int mt = blockIdx.x & 7;
  const int c  = blockIdx.x >> 3;        // chunk 0..127
  if (c == 0)
    run_chunk1<1>(x, yb, cf, lds, mt, 0, 8, 6, 510);
  else if (c == 127)                     // merged tail: stores e 65026..65590 (row<=16398)
    run_chunk1<0>(x, yb, cf, lds, mt, 512 * 127 - 253, 13, 255, 819);
  else
    run_chunk1<0>(x, yb, cf, lds, mt, 512 * c - 253, 12, 255, 763);
}

// ---------------- K2: backward chunked scan y -> quad-packed decimated output
// Slab-major yb reads (wave = one slab, sequential-descending 1KB rows) and
// slab-major ot2 writes. Bijective XCD swizzle: consecutive chunks (50% read
// overlap) share an L2.
__global__ __launch_bounds__(256) void k_bwd(const float* __restrict__ yb,
                                             float* __restrict__ ot2, Coefs cf) {
  const int id  = blockIdx.x;            // 0..513
  const int xcd = id & 7, pos = id >> 3; // hw XCD = id%8
  const int wgid = (xcd < 2 ? xcd * 65 : 130 + (xcd - 2) * 64) + pos;  // bijective
  const int c  = wgid % 257;
  const int by = wgid / 257;
  const int m  = by * 256 + threadIdx.x;
  const int mtY = m >> 6, chY = m & 63;
  const size_t slab  = (size_t)mtY * YB_ROWS * 256;   // slab base in floats
  const size_t slabq = (size_t)mtY * YB_ROWS * 64;    // ... in float4s
  const int own_lo = 256 * c;
  float z0, z1, z2, z3, z4, z5, z6, z7;
  int g_begin;
  if (c <= 1) {
    float y0 = yb[slab + (size_t)16398 * 256 + (size_t)chY * 4 + 2];   // s=65594 (u=0)
    z0 = cf.zi0 * y0; z1 = cf.zi1 * y0; z2 = cf.zi2 * y0; z3 = cf.zi3 * y0;
    z4 = cf.zi4 * y0; z5 = cf.zi5 * y0; z6 = cf.zi6 * y0; z7 = cf.zi7 * y0;
#pragma unroll
    for (int s = 65594; s >= 65584; --s) {       // u = 0..10 (no valid outputs)
      float yin = yb[slab + (size_t)(s >> 2) * 256 + (size_t)chY * 4 + (s & 3)];
      float wv; IIR_STEP(yin, wv);
      (void)wv;
    }
    g_begin = 16395;
  } else {
    g_begin = 16463 - 64 * c;                    // u=256c-261 at q3 of g_begin
    float y0 = yb[slab + (size_t)g_begin * 256 + (size_t)chY * 4 + 3];
    z0 = cf.zi0 * y0; z1 = cf.zi1 * y0; z2 = cf.zi2 * y0; z3 = cf.zi3 * y0;
    z4 = cf.zi4 * y0; z5 = cf.zi5 * y0; z6 = cf.zi6 * y0; z7 = cf.zi7 * y0;
  }
  const int g_stop = max(1, 16334 - 64 * c);
  const float4* yv = reinterpret_cast<const float4*>(yb);
  auto ld = [&](int r) {
    int rr = r < 0 ? 0 : r;
    return yv[slabq + (size_t)rr * 64 + chY];
  };
  float4 b0 = ld(g_begin), b1 = ld(g_begin - 1), b2 = ld(g_begin - 2), b3 = ld(g_begin - 3);
  float4 b4 = ld(g_begin - 4), b5 = ld(g_begin - 5), b6 = ld(g_begin - 6), b7 = ld(g_begin - 7);
  for (int g = g_begin; g >= g_stop; g -= 4) {
    float4 c0 = b0, c1 = b1, c2 = b2, c3 = b3;
    b0 = b4; b1 = b5; b2 = b6; b3 = b7;
    b4 = ld(g - 8); b5 = ld(g - 9); b6 = ld(g - 10); b7 = ld(g - 11);
    float4 pack;
#pragma unroll
    for (int j = 0; j < 4; ++j) {
      float4 q = (j == 0) ? c0 : (j == 1) ? c1 : (j == 2) ? c2 : c3;
      float w3, w2, w1, w0;
      IIR_STEP(q.w, w3);   // ascending u within group: q3,q2,q1,q0
      IIR_STEP(q.z, w2);
      IIR_STEP(q.y, w1);
      IIR_STEP(q.x, w0);
      (void)w3; (void)w2; (void)w1;
      if (j == 0) pack.w = w0;          // n = g-8
      else if (j == 1) pack.z = w0;     // n = g-9
      else if (j == 2) pack.y = w0;     // n = g-10
      else pack.x = w0;                 // n = g-11
    }
    if (65594 - 4 * g >= own_lo && g >= 11 && g <= 16391)
      *reinterpret_cast<float4*>(ot2 + ((size_t)mtY * 4096 + (size_t)((g - 11) >> 2)) * 256
                                 + (size_t)chY * 4) = pack;
  }
}

// ---------------- K3: slab-major ot2[mt][qn][64ch][4] -> out[m][16384] --------
__global__ __launch_bounds__(256) void k_outT(const float* __restrict__ ot2,
                                              float* __restrict__ out) {
  __shared__ float4 lds4[64 * 65];      // pitch 65 float4s: bank-perfect
  const int q0 = blockIdx.x * 64;       // quad tile (4096 quads total)
  const int my = blockIdx.y;            // slab = m-tile (64 ch)
  const int m0 = my * 64;
  const int tid = threadIdx.x;
  const float4* src = reinterpret_cast<const float4*>(ot2) + (size_t)my * 4096 * 64;
#pragma unroll
  for (int i = 0; i < 16; ++i) {
    int idx = tid + i * 256;
    int ql = idx >> 6;                  // wave-uniform
    int ml = idx & 63;                  // lane -> 1KB contiguous read
    lds4[ql * 65 + ml] = src[(size_t)(q0 + ql) * 64 + ml];
  }
  __syncthreads();
#pragma unroll
  for (int i = 0; i < 16; ++i) {
    int idx = tid + i * 256;
    int ml = idx >> 6;                  // wave-uniform
    int ql = idx & 63;                  // lane -> 1KB contiguous write
    float4 v = lds4[ql * 65 + ml];
    *reinterpret_cast<float4*>(
        out + (size_t)(m0 + ml) * 16384 + (size_t)(q0 + ql) * 4) = v;
  }
}

// ---------------- host: exact cheby1/zi design in double ----------------------
static void solve8(double Mm[8][9], double* zi) {
  for (int col = 0; col < 8; ++col) {
    int piv = col;
    for (int r = col + 1; r < 8; ++r)
      if (std::fabs(Mm[r][col]) > std::fabs(Mm[piv][col])) piv = r;
    if (piv != col)
      for (int j = 0; j < 9; ++j) { double t = Mm[col][j]; Mm[col][j] = Mm[piv][j]; Mm[piv][j] = t; }
    double d = Mm[col][col];
    for (int j = col; j < 9; ++j) Mm[col][j] /= d;
    for (int r = 0; r < 8; ++r)
      if (r != col) {
        double f = Mm[r][col];
        if (f != 0.0)
          for (int j = col; j < 9; ++j) Mm[r][j] -= f * Mm[col][j];
      }
  }
  for (int i = 0; i < 8; ++i) zi[i] = Mm[i][8];
}

static Coefs make_coefs() {
  using cd = std::complex<double>;
  const int N = 8;
  const double rp = 0.05, Wn = 0.8 / 4.0;
  double eps = std::sqrt(std::pow(10.0, 0.1 * rp) - 1.0);
  double mu = std::asinh(1.0 / eps) / N;
  cd p[8];
  for (int i = 0; i < N; ++i) {
    double th = M_PI * (2.0 * (i + 1) - 1.0) / (2.0 * N);
    p[i] = cd(-std::sinh(mu) * std::sin(th), std::cosh(mu) * std::cos(th));
  }
  cd pr(1.0, 0.0);
  for (int i = 0; i < N; ++i) pr *= -p[i];
  double g = pr.real();
  g /= std::sqrt(1.0 + eps * eps);                 // N even
  const double fs = 2.0;
  double warped = 2.0 * fs * std::tan(M_PI * Wn / fs);
  for (int i = 0; i < N; ++i) p[i] *= warped;
  g *= std::pow(warped, (double)N);
  const double fs2 = 2.0 * fs;
  cd pd[8], dpr(1.0, 0.0);
  for (int i = 0; i < N; ++i) {
    pd[i] = (cd(fs2, 0.0) + p[i]) / (cd(fs2, 0.0) - p[i]);
    dpr *= (cd(fs2, 0.0) - p[i]);
  }
  double gd = g * (cd(1.0, 0.0) / dpr).real();
  static const double binom[9] = {1, 8, 28, 56, 70, 56, 28, 8, 1};
  double b[9], a[9];
  for (int i = 0; i < 9; ++i) b[i] = gd * binom[i];
  cd cp[9]; cp[0] = cd(1, 0);
  for (int i = 1; i < 9; ++i) cp[i] = cd(0, 0);
  for (int i = 0; i < N; ++i)
    for (int j = i + 1; j >= 1; --j) cp[j] -= pd[i] * cp[j - 1];
  for (int i = 0; i < 9; ++i) a[i] = cp[i].real();
  double Mm[8][9];
  for (int i = 0; i < 8; ++i) {
    for (int j = 0; j < 9; ++j) Mm[i][j] = 0.0;
    Mm[i][0] += a[i + 1];
    Mm[i][i] += 1.0;
    if (i < 7) Mm[i][i + 1] = -1.0;
    Mm[i][8] = b[i + 1] - a[i + 1] * b[0];
  }
  double zi[8];
  solve8(Mm, zi);
  Coefs cf;
  cf.b0 = (float)b[0]; cf.b1 = (float)b[1]; cf.b2 = (float)b[2]; cf.b3 = (float)b[3];
  cf.b4 = (float)b[4]; cf.b5 = (float)b[5]; cf.b6 = (float)b[6]; cf.b7 = (float)b[7];
  cf.b8 = (float)b[8];
  cf.na1 = (float)(-a[1]); cf.na2 = (float)(-a[2]); cf.na3 = (float)(-a[3]);
  cf.na4 = (float)(-a[4]); cf.na5 = (float)(-a[5]); cf.na6 = (float)(-a[6]);
  cf.na7 = (float)(-a[7]); cf.na8 = (float)(-a[8]);
  cf.zi0 = (float)zi[0]; cf.zi1 = (float)zi[1]; cf.zi2 = (float)zi[2]; cf.zi3 = (float)zi[3];
  cf.zi4 = (float)zi[4]; cf.zi5 = (float)zi[5]; cf.zi6 = (float)zi[6]; cf.zi7 = (float)zi[7];
  return cf;
}

}  // namespace

extern "C" void kernel_launch(void* const* d_in, const int* in_sizes, int n_in,
                              void* d_out, int out_size, void* d_ws, size_t ws_size,
                              hipStream_t stream) {
  (void)in_sizes; (void)n_in; (void)out_size; (void)ws_size;
  const float* x = (const float*)d_in[0];
  float* out = (float*)d_out;
  float* yb  = (float*)d_ws;                       // 134.4 MB (8 slabs)
  float* ot2 = yb + YB_ROWS * 2048;                // 33.6 MB (8 slabs)
  Coefs cf = make_coefs();                         // pure host math, capture-safe
  hipLaunchKernelGGL(k_fwd4, dim3(1024), dim3(64), 0, stream, x, yb, cf);
  hipLaunchKernelGGL(k_bwd, dim3(514), dim3(256), 0, stream, yb, ot2, cf);
  hipLaunchKernelGGL(k_outT, dim3(4096 / 64, NCH / 64), dim3(256), 0, stream, ot2, out);
}

// Round 4
// 292.189 us; speedup vs baseline: 1.2197x; 1.2197x over previous
//
#include <hip/hip_runtime.h>
#include <cmath>
#include <complex>

namespace {

constexpr int TLEN   = 65536;
constexpr int NCH    = 512;            // 32*16 channels
constexpr size_t YB_ROWS = 16400;      // float4-groups in yb (valid g <= 16398)

// yb layout (round-0, proven): sample e at row s=e+5, float offset
// (s>>2)*2048 + ch*4 + (s&3). 1KB-contiguous per (group, 64ch tile).

struct Coefs {
  float b0,b1,b2,b3,b4,b5,b6,b7,b8;
  float na1,na2,na3,na4,na5,na6,na7,na8;   // -a[1..8]
  float zi0,zi1,zi2,zi3,zi4,zi5,zi6,zi7;
};

#define IIR_STEP(xv, yv)                                  \
  do {                                                    \
    yv = fmaf(cf.b0, (xv), z0);                           \
    z0 = fmaf(cf.na1, yv, fmaf(cf.b1, (xv), z1));         \
    z1 = fmaf(cf.na2, yv, fmaf(cf.b2, (xv), z2));         \
    z2 = fmaf(cf.na3, yv, fmaf(cf.b3, (xv), z3));         \
    z3 = fmaf(cf.na4, yv, fmaf(cf.b4, (xv), z4));         \
    z4 = fmaf(cf.na5, yv, fmaf(cf.b5, (xv), z5));         \
    z5 = fmaf(cf.na6, yv, fmaf(cf.b6, (xv), z6));         \
    z6 = fmaf(cf.na7, yv, fmaf(cf.b7, (xv), z7));         \
    z7 = fmaf(cf.na8, yv, cf.b8 * (xv));                  \
  } while (0)

// =============== K1: fused extension+transpose+forward scan ==================
// Round-0 structure (proven FETCH=110MB / WRITE=131MB): 4-wave blocks, wave 0
// scans, all waves stage. Edit vs round 0: 2-ring LDS (33.3KB -> 4 blocks/CU,
// was 3-ring/50.2KB/3 blocks) with issue-1-ahead (loads get the full ~3000cyc
// scan to land; depth-2 unnecessary).
template<int QOFF, bool VEC>
__device__ __forceinline__ void run_chunk(const float* __restrict__ x,
                                          float* __restrict__ yb,
                                          const Coefs& cf,
                                          float (&lds)[2][4160],
                                          int m0, int e0, int nsub,
                                          int store_lo, int store_hi) {
  const int tid  = threadIdx.x;
  const int lane = tid & 63;
  const int vtbase = e0 - 27;            // x-index of e0
  const int mIdx = m0 + lane;
  float4* yq = reinterpret_cast<float4*>(yb);
  const int tq  = tid & 15;              // VEC: float4-column within row
  const int chb = tid >> 4;              // VEC: base channel row (0..15)
  float4 rr0, rr1, rr2, rr3;             // VEC staging
  float rs[16];                          // edge staging

  auto issue = [&](int k) {
    const int vt0 = vtbase + 64 * k;
    if (VEC) {
      const float* p = x + (size_t)(m0 + chb) * TLEN + vt0 + 4 * tq;
      rr0 = *reinterpret_cast<const float4*>(p);
      rr1 = *reinterpret_cast<const float4*>(p + (size_t)16 * TLEN);
      rr2 = *reinterpret_cast<const float4*>(p + (size_t)32 * TLEN);
      rr3 = *reinterpret_cast<const float4*>(p + (size_t)48 * TLEN);
    } else {
#pragma unroll
      for (int i = 0; i < 16; ++i) {
        int idx = tid + 256 * i;
        int tl = idx & 63, ch = idx >> 6;
        int vt = vt0 + tl;
        const float* xr = x + (size_t)(m0 + ch) * TLEN;
        float v;
        if (vt < 0) v = 2.0f * xr[0] - xr[-vt];
        else if (vt >= TLEN) v = 2.0f * xr[TLEN - 1] - xr[2 * TLEN - 2 - vt];
        else v = xr[vt];
        rs[i] = v;
      }
    }
  };
  auto commit = [&](int k) {
    float* b = lds[k & 1];
    if (VEC) {
      const int base = 4 * tq * 65;
      b[base       + chb     ] = rr0.x; b[base + 65  + chb     ] = rr0.y;
      b[base + 130 + chb     ] = rr0.z; b[base + 195 + chb     ] = rr0.w;
      b[base       + chb + 16] = rr1.x; b[base + 65  + chb + 16] = rr1.y;
      b[base + 130 + chb + 16] = rr1.z; b[base + 195 + chb + 16] = rr1.w;
      b[base       + chb + 32] = rr2.x; b[base + 65  + chb + 32] = rr2.y;
      b[base + 130 + chb + 32] = rr2.z; b[base + 195 + chb + 32] = rr2.w;
      b[base       + chb + 48] = rr3.x; b[base + 65  + chb + 48] = rr3.y;
      b[base + 130 + chb + 48] = rr3.z; b[base + 195 + chb + 48] = rr3.w;
    } else {
#pragma unroll
      for (int i = 0; i < 16; ++i) {
        int idx = tid + 256 * i;
        int tl = idx & 63, ch = idx >> 6;
        b[tl * 65 + ch] = rs[i];
      }
    }
  };

  // prologue: subtile 0 only (2-ring, depth 1)
  issue(0); commit(0);

  float z0 = 0, z1 = 0, z2 = 0, z3 = 0, z4 = 0, z5 = 0, z6 = 0, z7 = 0;
  float4 oq = make_float4(0.f, 0.f, 0.f, 0.f);

  for (int k = 0; k < nsub; ++k) {
    if (k + 1 < nsub) issue(k + 1);      // loads in flight across the barrier
    __syncthreads();                     // buf k&1 committed (end of iter k-1)
    if (k == 0 && tid < 64) {
      float x0 = lds[0][lane];           // x_ext(e0)
      z0 = cf.zi0 * x0; z1 = cf.zi1 * x0; z2 = cf.zi2 * x0; z3 = cf.zi3 * x0;
      z4 = cf.zi4 * x0; z5 = cf.zi5 * x0; z6 = cf.zi6 * x0; z7 = cf.zi7 * x0;
    }
    if (tid < 64) {
      const float* tile = lds[k & 1];
#pragma unroll
      for (int tl = 0; tl < 64; ++tl) {
        float xin = tile[tl * 65 + lane];
        float yv; IIR_STEP(xin, yv);
        if (QOFF == 1) {                   // c==0 scalar head e=0,1,2 (grp1 q1..3)
          if (k == 0 && tl < 3) yb[2048 + mIdx * 4 + tl + 1] = yv;
        }
        const int q = (tl + QOFF) & 3;     // q = (e+1)&3, static after unroll
        if (q == 0) oq.x = yv;
        else if (q == 1) oq.y = yv;
        else if (q == 2) oq.z = yv;
        else {
          oq.w = yv;
          const int step = 64 * k + tl;
          if (step >= store_lo && step <= store_hi)
            yq[(size_t)((e0 + step + 5) >> 2) * 512 + mIdx] = oq;
        }
      }
    }
    if (k + 1 < nsub) commit(k + 1);     // writes buf (k+1)&1 (scan reads k&1)
  }
}

__global__ __launch_bounds__(256) void k_fwd2(const float* __restrict__ x,
                                              float* __restrict__ yb, Coefs cf) {
  __shared__ float lds[2][4160];           // 33.3 KB -> 4 blocks/CU
  const int c  = blockIdx.x;               // chunk 0..128
  const int m0 = blockIdx.y * 64;          // channel tile
  if (c == 0)
    run_chunk<1, false>(x, yb, cf, lds, m0, 0, 8, 6, 510);
  else if (c == 128)
    run_chunk<0, false>(x, yb, cf, lds, m0, 65283, 5, 255, 307);
  else
    run_chunk<0, true>(x, yb, cf, lds, m0, 512 * c - 253, 12, 255, 763);
}

// ---------------- K2: backward chunked scan -> out, fused transpose ----------
// 256 chunks x 2 channel-halves (512 blocks = exactly 2/CU at 66.6KB LDS).
// Chunk c owns out cols [64c, 64c+63] (col i <-> s = 4i+32). Scan g from
// 64c+139 down to 64c+11 (warm-up 275 >= 261 steps); c==255 takes the exact
// zi-init path (s=65594 preamble). Packs staged in pitch-65 LDS (bank-free),
// then written to out as 256B-per-channel coalesced segments. No ot2, no k_outT.
__global__ __launch_bounds__(256) void k_bwd2(const float* __restrict__ yb,
                                              float* __restrict__ out, Coefs cf) {
  __shared__ float wl[256 * 65];         // [ch][64 cols], pitch 65 -> 66.6KB
  const int c   = blockIdx.x;            // 0..255
  const int tid = threadIdx.x;
  const int m   = blockIdx.y * 256 + tid;
  float z0, z1, z2, z3, z4, z5, z6, z7;
  int g_begin;
  if (c == 255) {                        // exact filtfilt backward init
    float y0 = yb[(size_t)16398 * 2048 + (size_t)m * 4 + 2];   // s=65594 (u=0)
    z0 = cf.zi0 * y0; z1 = cf.zi1 * y0; z2 = cf.zi2 * y0; z3 = cf.zi3 * y0;
    z4 = cf.zi4 * y0; z5 = cf.zi5 * y0; z6 = cf.zi6 * y0; z7 = cf.zi7 * y0;
#pragma unroll
    for (int s = 65594; s >= 65584; --s) {       // u = 0..10 (no owned outputs)
      float yin = yb[(size_t)(s >> 2) * 2048 + (size_t)m * 4 + (s & 3)];
      float wv; IIR_STEP(yin, wv);
      (void)wv;
    }
    g_begin = 16395;
  } else {
    g_begin = 64 * c + 139;                      // warm-up init at q3 of g_begin
    float y0 = yb[(size_t)g_begin * 2048 + (size_t)m * 4 + 3];
    z0 = cf.zi0 * y0; z1 = cf.zi1 * y0; z2 = cf.zi2 * y0; z3 = cf.zi3 * y0;
    z4 = cf.zi4 * y0; z5 = cf.zi5 * y0; z6 = cf.zi6 * y0; z7 = cf.zi7 * y0;
  }
  const int g_stop = 64 * c + 11;        // last pack: col-base 64c
  const int g_hi   = 64 * c + 71;        // first owned pack: col-base 64c+60
  const float4* yv = reinterpret_cast<const float4*>(yb);
  auto ld = [&](int r) {
    int rr = r < 0 ? 0 : r;
    return yv[(size_t)rr * 512 + m];
  };
  float4 b0 = ld(g_begin), b1 = ld(g_begin - 1), b2 = ld(g_begin - 2), b3 = ld(g_begin - 3);
  float4 b4 = ld(g_begin - 4), b5 = ld(g_begin - 5), b6 = ld(g_begin - 6), b7 = ld(g_begin - 7);
  for (int g = g_begin; g >= g_stop; g -= 4) {
    float4 c0 = b0, c1 = b1, c2 = b2, c3 = b3;
    b0 = b4; b1 = b5; b2 = b6; b3 = b7;
    b4 = ld(g - 8); b5 = ld(g - 9); b6 = ld(g - 10); b7 = ld(g - 11);
    float4 pack;
#pragma unroll
    for (int j = 0; j < 4; ++j) {
      float4 q = (j == 0) ? c0 : (j == 1) ? c1 : (j == 2) ? c2 : c3;
      float w3, w2, w1, w0;
      IIR_STEP(q.w, w3);   // ascending u within group: q3,q2,q1,q0
      IIR_STEP(q.z, w2);
      IIR_STEP(q.y, w1);
      IIR_STEP(q.x, w0);
      (void)w3; (void)w2; (void)w1;
      if (j == 0) pack.w = w0;          // col g-8
      else if (j == 1) pack.z = w0;     // col g-9
      else if (j == 2) pack.y = w0;     // col g-10
      else pack.x = w0;                 // col g-11
    }
    if (g <= g_hi) {                    // owned packs: col-base (g-11) in [64c, 64c+60]
      const int cb = g - 11 - 64 * c;   // wave-uniform 0..60
      wl[tid * 65 + cb    ] = pack.x;   // banks (tid+cb)%32: 2-way, free
      wl[tid * 65 + cb + 1] = pack.y;
      wl[tid * 65 + cb + 2] = pack.z;
      wl[tid * 65 + cb + 3] = pack.w;
    }
  }
  __syncthreads();
  // out write: per instr, 4 channels x 256B contiguous (16 lanes x float4 each)
  const int colb = 64 * c;
#pragma unroll
  for (int i = 0; i < 16; ++i) {
    int idx = tid + i * 256;            // 0..4095 = 256 ch x 16 float4-cols
    int ch  = idx >> 4;
    int f4  = idx & 15;
    float4 v = make_float4(wl[ch * 65 + 4 * f4],     wl[ch * 65 + 4 * f4 + 1],
                           wl[ch * 65 + 4 * f4 + 2], wl[ch * 65 + 4 * f4 + 3]);
    *reinterpret_cast<float4*>(
        out + (size_t)(blockIdx.y * 256 + ch) * 16384 + colb + 4 * f4) = v;
  }
}

// ---------------- host: exact cheby1/zi design in double ----------------------
static void solve8(double Mm[8][9], double* zi) {
  for (int col = 0; col < 8; ++col) {
    int piv = col;
    for (int r = col + 1; r < 8; ++r)
      if (std::fabs(Mm[r][col]) > std::fabs(Mm[piv][col])) piv = r;
    if (piv != col)
      for (int j = 0; j < 9; ++j) { double t = Mm[col][j]; Mm[col][j] = Mm[piv][j]; Mm[piv][j] = t; }
    double d = Mm[col][col];
    for (int j = col; j < 9; ++j) Mm[col][j] /= d;
    for (int r = 0; r < 8; ++r)
      if (r != col) {
        double f = Mm[r][col];
        if (f != 0.0)
          for (int j = col; j < 9; ++j) Mm[r][j] -= f * Mm[col][j];
      }
  }
  for (int i = 0; i < 8; ++i) zi[i] = Mm[i][8];
}

static Coefs make_coefs() {
  using cd = std::complex<double>;
  const int N = 8;
  const double rp = 0.05, Wn = 0.8 / 4.0;
  double eps = std::sqrt(std::pow(10.0, 0.1 * rp) - 1.0);
  double mu = std::asinh(1.0 / eps) / N;
  cd p[8];
  for (int i = 0; i < N; ++i) {
    double th = M_PI * (2.0 * (i + 1) - 1.0) / (2.0 * N);
    p[i] = cd(-std::sinh(mu) * std::sin(th), std::cosh(mu) * std::cos(th));
  }
  cd pr(1.0, 0.0);
  for (int i = 0; i < N; ++i) pr *= -p[i];
  double g = pr.real();
  g /= std::sqrt(1.0 + eps * eps);                 // N even
  const double fs = 2.0;
  double warped = 2.0 * fs * std::tan(M_PI * Wn / fs);
  for (int i = 0; i < N; ++i) p[i] *= warped;
  g *= std::pow(warped, (double)N);
  const double fs2 = 2.0 * fs;
  cd pd[8], dpr(1.0, 0.0);
  for (int i = 0; i < N; ++i) {
    pd[i] = (cd(fs2, 0.0) + p[i]) / (cd(fs2, 0.0) - p[i]);
    dpr *= (cd(fs2, 0.0) - p[i]);
  }
  double gd = g * (cd(1.0, 0.0) / dpr).real();
  static const double binom[9] = {1, 8, 28, 56, 70, 56, 28, 8, 1};
  double b[9], a[9];
  for (int i = 0; i < 9; ++i) b[i] = gd * binom[i];
  cd cp[9]; cp[0] = cd(1, 0);
  for (int i = 1; i < 9; ++i) cp[i] = cd(0, 0);
  for (int i = 0; i < N; ++i)
    for (int j = i + 1; j >= 1; --j) cp[j] -= pd[i] * cp[j - 1];
  for (int i = 0; i < 9; ++i) a[i] = cp[i].real();
  double Mm[8][9];
  for (int i = 0; i < 8; ++i) {
    for (int j = 0; j < 9; ++j) Mm[i][j] = 0.0;
    Mm[i][0] += a[i + 1];
    Mm[i][i] += 1.0;
    if (i < 7) Mm[i][i + 1] = -1.0;
    Mm[i][8] = b[i + 1] - a[i + 1] * b[0];
  }
  double zi[8];
  solve8(Mm, zi);
  Coefs cf;
  cf.b0 = (float)b[0]; cf.b1 = (float)b[1]; cf.b2 = (float)b[2]; cf.b3 = (float)b[3];
  cf.b4 = (float)b[4]; cf.b5 = (float)b[5]; cf.b6 = (float)b[6]; cf.b7 = (float)b[7];
  cf.b8 = (float)b[8];
  cf.na1 = (float)(-a[1]); cf.na2 = (float)(-a[2]); cf.na3 = (float)(-a[3]);
  cf.na4 = (float)(-a[4]); cf.na5 = (float)(-a[5]); cf.na6 = (float)(-a[6]);
  cf.na7 = (float)(-a[7]); cf.na8 = (float)(-a[8]);
  cf.zi0 = (float)zi[0]; cf.zi1 = (float)zi[1]; cf.zi2 = (float)zi[2]; cf.zi3 = (float)zi[3];
  cf.zi4 = (float)zi[4]; cf.zi5 = (float)zi[5]; cf.zi6 = (float)zi[6]; cf.zi7 = (float)zi[7];
  return cf;
}

}  // namespace

extern "C" void kernel_launch(void* const* d_in, const int* in_sizes, int n_in,
                              void* d_out, int out_size, void* d_ws, size_t ws_size,
                              hipStream_t stream) {
  (void)in_sizes; (void)n_in; (void)out_size; (void)ws_size;
  const float* x = (const float*)d_in[0];
  float* out = (float*)d_out;
  float* yb  = (float*)d_ws;                       // 134.4 MB (round-0 layout)
  Coefs cf = make_coefs();                         // pure host math, capture-safe
  hipLaunchKernelGGL(k_fwd2, dim3(129, NCH / 64), dim3(256), 0, stream, x, yb, cf);
  hipLaunchKernelGGL(k_bwd2, dim3(256, 2), dim3(256), 0, stream, yb, out, cf);
}